// Round 5
// baseline (95875.574 us; speedup 1.0000x reference)
//
#include <hip/hip_runtime.h>

#define NB 128
#define NT 256
#define NA 8
#define NH 1024

__device__ __forceinline__ float sigm_f(float u)  { return 1.f / (1.f + __expf(-u)); }
// overflow-safe tanh
__device__ __forceinline__ float tanh_f(float u)  { return 1.f - 2.f / (1.f + __expf(2.f * u)); }

// ---------------------------------------------------------------------------
// Phase 1: x[b,t,h] = relu(actions[b,t,:]·fc_w[h,:] + fc_b[h]) -> fp32,
// stored into d_out (x scratch). Step t reads slice t and writes slice t-1,
// so no slice is ever read after being overwritten.
// ---------------------------------------------------------------------------
__global__ __launch_bounds__(256) void xproj_kernel(
    const float* __restrict__ actions,   // [B,T,A] fp32
    const float* __restrict__ fc_w,      // [H,A]  fp32
    const float* __restrict__ fc_b,      // [H]    fp32
    float* __restrict__ xbuf)            // [B,T,H] fp32 (= d_out)
{
    const int bt  = blockIdx.x;       // b*T + t
    const int tid = threadIdx.x;

    const float* ap = actions + (size_t)bt * NA;
    float a[8];
#pragma unroll
    for (int i = 0; i < 8; ++i) a[i] = ap[i];

    const int h0 = tid * 4;
    float4 r;
    float* rp = &r.x;
#pragma unroll
    for (int j = 0; j < 4; ++j) {
        const float* wp = fc_w + (size_t)(h0 + j) * NA;
        float acc = fc_b[h0 + j];
#pragma unroll
        for (int i = 0; i < 8; ++i) acc += a[i] * wp[i];
        rp[j] = fmaxf(acc, 0.f);
    }
    *(float4*)(xbuf + (size_t)bt * NH + h0) = r;
}

// ---------------------------------------------------------------------------
// hF slot 0 <- hidden0 (fp32 copy)
// ---------------------------------------------------------------------------
__global__ __launch_bounds__(512) void hinit_kernel(
    const float* __restrict__ hidden0, float* __restrict__ hF)
{
    const int i = blockIdx.x * 512 + threadIdx.x;   // grid 256 -> 131072 = B*H
    hF[i] = hidden0[i];
}

// ---------------------------------------------------------------------------
// One GRU step, pure fp32 VALU.
// Grid 256 blocks: (bb 0..3 -> 32 batch rows) x (hc 0..63 -> 16 h outputs).
// Block 512 threads: thread owns (b = tid>>4, hl = tid&15), computes six
// 1024-long dot products (r,z,n for w_hh and w_ih) in fp32, applies gates,
// writes hF slot (t+1)&1 and out slice t-1 (= h_t, the hprev it already has).
// blockIdx = bb*64+hc -> XCD = hc%8: all 4 bb-sharers of an hc hit the same
// XCD L2, so each weight row is L2-resident after the first step.
// ---------------------------------------------------------------------------
__global__ __launch_bounds__(512) void gru_step_valu(
    float* xout,                           // d_out: x slices (read t) + out (write t-1)
    const float* __restrict__ w_ih,        // [3H,H] fp32
    const float* __restrict__ w_hh,        // [3H,H] fp32
    const float* __restrict__ b_ih,        // [3H] fp32
    const float* __restrict__ b_hh,        // [3H] fp32
    float* __restrict__ hF,                // ws: [2][B][H] fp32 ping-pong
    int t)
{
    const int tid = threadIdx.x;
    const int b   = tid >> 4;              // 0..31
    const int hl  = tid & 15;              // 0..15
    const int bb  = blockIdx.x >> 6;       // 0..3
    const int hc  = blockIdx.x & 63;       // 0..63
    const int bg  = bb * 32 + b;
    const int hg  = hc * 16 + hl;

    const float* hrow = hF + (size_t)(t & 1) * (NB * NH) + (size_t)bg * NH;
    const float* xrow = xout + ((size_t)bg * NT + t) * NH;

    const float* wrh = w_hh + (size_t)(0 * NH + hg) * NH;
    const float* wzh = w_hh + (size_t)(1 * NH + hg) * NH;
    const float* wnh = w_hh + (size_t)(2 * NH + hg) * NH;
    const float* wrx = w_ih + (size_t)(0 * NH + hg) * NH;
    const float* wzx = w_ih + (size_t)(1 * NH + hg) * NH;
    const float* wnx = w_ih + (size_t)(2 * NH + hg) * NH;

    float hr = 0.f, hz = 0.f, hn = 0.f, xr = 0.f, xz = 0.f, xn = 0.f;
#pragma unroll 4
    for (int k = 0; k < NH; k += 4) {
        float4 hv = *(const float4*)(hrow + k);
        float4 xv = *(const float4*)(xrow + k);
        float4 w;
        w = *(const float4*)(wrh + k); hr += hv.x*w.x + hv.y*w.y + hv.z*w.z + hv.w*w.w;
        w = *(const float4*)(wzh + k); hz += hv.x*w.x + hv.y*w.y + hv.z*w.z + hv.w*w.w;
        w = *(const float4*)(wnh + k); hn += hv.x*w.x + hv.y*w.y + hv.z*w.z + hv.w*w.w;
        w = *(const float4*)(wrx + k); xr += xv.x*w.x + xv.y*w.y + xv.z*w.z + xv.w*w.w;
        w = *(const float4*)(wzx + k); xz += xv.x*w.x + xv.y*w.y + xv.z*w.z + xv.w*w.w;
        w = *(const float4*)(wnx + k); xn += xv.x*w.x + xv.y*w.y + xv.z*w.z + xv.w*w.w;
    }

    const float XR = xr + b_ih[0 * NH + hg];
    const float XZ = xz + b_ih[1 * NH + hg];
    const float XN = xn + b_ih[2 * NH + hg];
    const float HR = hr + b_hh[0 * NH + hg];
    const float HZ = hz + b_hh[1 * NH + hg];
    const float HN = hn + b_hh[2 * NH + hg];

    const float r = sigm_f(XR + HR);
    const float z = sigm_f(XZ + HZ);
    const float n = tanh_f(XN + r * HN);
    const float hprev = hrow[hg];
    const float hnew  = (1.f - z) * n + z * hprev;

    hF[(size_t)((t + 1) & 1) * (NB * NH) + (size_t)bg * NH + hg] = hnew;

    // delayed out-write: out[t-1] = h_t = hprev (slice t-1's x already consumed)
    if (t > 0)
        xout[((size_t)bg * NT + (t - 1)) * NH + hg] = hprev;
}

// ---------------------------------------------------------------------------
// Tail: out[:, T-1, :] = h_T (hF slot 0 after step T-1, since (255+1)&1 = 0)
// ---------------------------------------------------------------------------
__global__ __launch_bounds__(512) void tail_kernel(
    const float* __restrict__ hF, float* __restrict__ xout)
{
    const int i = blockIdx.x * 512 + threadIdx.x;   // 0 .. B*H-1
    const int b = i >> 10;
    const int h = i & (NH - 1);
    xout[((size_t)b * NT + (NT - 1)) * NH + h] = hF[i];
}

extern "C" void kernel_launch(void* const* d_in, const int* in_sizes, int n_in,
                              void* d_out, int out_size, void* d_ws, size_t ws_size,
                              hipStream_t stream)
{
    (void)in_sizes; (void)n_in; (void)out_size; (void)ws_size;

    const float* actions = (const float*)d_in[0];
    const float* hidden  = (const float*)d_in[1];
    const float* fc_w    = (const float*)d_in[2];
    const float* fc_b    = (const float*)d_in[3];
    const float* w_ih    = (const float*)d_in[4];
    const float* w_hh    = (const float*)d_in[5];
    const float* b_ih    = (const float*)d_in[6];
    const float* b_hh    = (const float*)d_in[7];

    float* xout = (float*)d_out;         // fp32: x scratch, then output
    float* hF   = (float*)d_ws;          // 2*128*1024*4 = 1,048,576 B

    xproj_kernel<<<dim3(NB * NT), dim3(256), 0, stream>>>(actions, fc_w, fc_b, xout);
    hinit_kernel<<<dim3(256), dim3(512), 0, stream>>>(hidden, hF);
    for (int t = 0; t < NT; ++t)
        gru_step_valu<<<dim3(256), dim3(512), 0, stream>>>(xout, w_ih, w_hh,
                                                           b_ih, b_hh, hF, t);
    tail_kernel<<<dim3(256), dim3(512), 0, stream>>>(hF, xout);
}

// Round 6
// 3992.086 us; speedup vs baseline: 24.0164x; 24.0164x over previous
//
#include <hip/hip_runtime.h>

typedef __attribute__((ext_vector_type(8))) short short8;   // 8 x bf16 (4 VGPRs)
typedef __attribute__((ext_vector_type(4))) float f32x4;

#define NB 128
#define NT 256
#define NA 8
#define NH 1024
#define NG 3072   // 3*NH

__device__ __forceinline__ unsigned short f2bf(float f) {
    unsigned v;
    __builtin_memcpy(&v, &f, 4);
    v = v + 0x7fffu + ((v >> 16) & 1u);   // round-to-nearest-even
    return (unsigned short)(v >> 16);
}
__device__ __forceinline__ float sigm_f(float u)  { return 1.f / (1.f + __expf(-u)); }
// overflow-safe tanh
__device__ __forceinline__ float tanh_f(float u)  { return 1.f - 2.f / (1.f + __expf(2.f * u)); }

// ===========================================================================
// FAST PATH (MFMA) — needs ~84.4 MB ws
// ===========================================================================

// fp32 -> bf16 pack (weights)
__global__ __launch_bounds__(256) void wconv_kernel(
    const float* __restrict__ src, unsigned short* __restrict__ dst, int n)
{
    for (int i = (blockIdx.x * 256 + threadIdx.x) * 4; i < n; i += gridDim.x * 256 * 4) {
        float4 v = *(const float4*)(src + i);
        ushort4 o;
        o.x = f2bf(v.x); o.y = f2bf(v.y); o.z = f2bf(v.z); o.w = f2bf(v.w);
        *(ushort4*)(dst + i) = o;
    }
}

// x[b,t,h] = relu(actions[b,t,:]·fc_w[h,:] + fc_b[h]) -> bf16 into ws
__global__ __launch_bounds__(256) void xproj_bf16_kernel(
    const float* __restrict__ actions,   // [B,T,A] fp32
    const float* __restrict__ fc_w,      // [H,A]  fp32
    const float* __restrict__ fc_b,      // [H]    fp32
    unsigned short* __restrict__ xbf)    // [B,T,H] bf16 (ws)
{
    const int bt  = blockIdx.x;
    const int tid = threadIdx.x;

    const float* ap = actions + (size_t)bt * NA;
    float a[8];
#pragma unroll
    for (int i = 0; i < 8; ++i) a[i] = ap[i];

    const int h0 = tid * 4;
    unsigned short r[4];
#pragma unroll
    for (int j = 0; j < 4; ++j) {
        const float* wp = fc_w + (size_t)(h0 + j) * NA;
        float acc = fc_b[h0 + j];
#pragma unroll
        for (int i = 0; i < 8; ++i) acc += a[i] * wp[i];
        r[j] = f2bf(fmaxf(acc, 0.f));
    }
    ushort4 pk;
    pk.x = r[0]; pk.y = r[1]; pk.z = r[2]; pk.w = r[3];
    *(ushort4*)(xbf + (size_t)bt * NH + h0) = pk;
}

// ---------------------------------------------------------------------------
// Block tile: (bb 0..3 -> 32 batch rows) x (hc 0..63 -> 16 h outputs = 48
// gate rows). 4 waves k-split K=1024 into 256 each; partials reduced in LDS.
// MFMA 16x16x32 bf16.  A: lane holds A[m=lane&15][k=(lane>>4)*8+j].
//                      B: lane holds B[k=(lane>>4)*8+j][n=lane&15].
//                      D: lane reg i holds D[m=(lane>>4)*4+i][n=lane&15].
// blockIdx = bb*64+hc -> XCD = hc%8: all 4 bb-sharers of an hc on one XCD;
// per-XCD weight working set 1.6 MB -> L2-resident after step 0.
// ---------------------------------------------------------------------------
__device__ __forceinline__ void xq_gemm(
    const unsigned short* xslice,   // xbf + t*NH
    const unsigned short* w_ih,     // bf16 [3H,H]
    int bb, int hc, int col, int koff, f32x4 acc[6])
{
    const unsigned short* Ax = xslice + (size_t)(bb * 32 + col) * (NT * NH) + koff;
    const size_t tile1 = (size_t)16 * NT * NH;
    const unsigned short* W0 = w_ih + (size_t)(0 * NH + hc * 16 + col) * NH + koff;
    const unsigned short* W1 = w_ih + (size_t)(1 * NH + hc * 16 + col) * NH + koff;
    const unsigned short* W2 = w_ih + (size_t)(2 * NH + hc * 16 + col) * NH + koff;
#pragma unroll
    for (int s = 0; s < 8; ++s) {
        short8 a0 = *(const short8*)(Ax + s * 32);
        short8 a1 = *(const short8*)(Ax + tile1 + s * 32);
        short8 b0 = *(const short8*)(W0 + s * 32);
        short8 b1 = *(const short8*)(W1 + s * 32);
        short8 b2 = *(const short8*)(W2 + s * 32);
        acc[0] = __builtin_amdgcn_mfma_f32_16x16x32_bf16(a0, b0, acc[0], 0, 0, 0);
        acc[1] = __builtin_amdgcn_mfma_f32_16x16x32_bf16(a0, b1, acc[1], 0, 0, 0);
        acc[2] = __builtin_amdgcn_mfma_f32_16x16x32_bf16(a0, b2, acc[2], 0, 0, 0);
        acc[3] = __builtin_amdgcn_mfma_f32_16x16x32_bf16(a1, b0, acc[3], 0, 0, 0);
        acc[4] = __builtin_amdgcn_mfma_f32_16x16x32_bf16(a1, b1, acc[4], 0, 0, 0);
        acc[5] = __builtin_amdgcn_mfma_f32_16x16x32_bf16(a1, b2, acc[5], 0, 0, 0);
    }
}

// Init: xp slot0 = x[:,0,:]·w_ih^T ; hF/hB slot0 from fp32 hidden0.
__global__ __launch_bounds__(256) void gru_init_kernel(
    const unsigned short* __restrict__ xbf,
    const float* __restrict__ hidden0,
    const unsigned short* __restrict__ w_ih,
    float* __restrict__ xp,                       // [2][B][3H] fp32
    float* __restrict__ hF,                       // [2][B][H] fp32
    unsigned short* __restrict__ hB)              // [2][B][H] bf16
{
    const int tid = threadIdx.x;
    const int kw = tid >> 6, lane = tid & 63, col = lane & 15, q = lane >> 4;
    const int bb = blockIdx.x >> 6, hc = blockIdx.x & 63;
    const int koff = kw * 256 + q * 8;

    __shared__ float xq_d[4][32][49];

    f32x4 acc[6];
#pragma unroll
    for (int i = 0; i < 6; ++i) acc[i] = (f32x4){0.f, 0.f, 0.f, 0.f};
    xq_gemm(xbf, w_ih, bb, hc, col, koff, acc);   // t = 0

#pragma unroll
    for (int m = 0; m < 2; ++m)
#pragma unroll
        for (int n = 0; n < 3; ++n)
#pragma unroll
            for (int i = 0; i < 4; ++i)
                xq_d[kw][m * 16 + q * 4 + i][n * 16 + col] = acc[m * 3 + n][i];
    __syncthreads();

    const int b = tid >> 3, h2 = (tid & 7) * 2, bg = bb * 32 + b;
#pragma unroll
    for (int e = 0; e < 2; ++e) {
        const int hl = h2 + e;
        const int hg = hc * 16 + hl;
        float s0 = 0.f, s1 = 0.f, s2 = 0.f;
#pragma unroll
        for (int c = 0; c < 4; ++c) {
            s0 += xq_d[c][b][hl];
            s1 += xq_d[c][b][16 + hl];
            s2 += xq_d[c][b][32 + hl];
        }
        float* xpd = xp + (size_t)bg * NG;       // slot 0
        xpd[hg]          = s0;
        xpd[NH + hg]     = s1;
        xpd[2 * NH + hg] = s2;
        const float hv = hidden0[(size_t)bg * NH + hg];
        hF[(size_t)bg * NH + hg] = hv;
        hB[(size_t)bg * NH + hg] = f2bf(hv);
    }
}

// One GRU timestep (MFMA). out written fp32 to d_out.
__global__ __launch_bounds__(256) void gru_step_kernel(
    float* __restrict__ out,                      // d_out [B,T,H] fp32
    const unsigned short* __restrict__ xbf,       // ws x bf16
    const unsigned short* __restrict__ w_ih,      // ws bf16
    const unsigned short* __restrict__ w_hh,      // ws bf16
    const float* __restrict__ b_ih,
    const float* __restrict__ b_hh,
    float* __restrict__ xp,                       // [2][B][3H] fp32
    float* __restrict__ hF,                       // [2][B][H] fp32
    unsigned short* __restrict__ hB,              // [2][B][H] bf16
    int t)
{
    const int tid = threadIdx.x;
    const int kw = tid >> 6, lane = tid & 63, col = lane & 15, q = lane >> 4;
    const int bb = blockIdx.x >> 6, hc = blockIdx.x & 63;
    const int koff = kw * 256 + q * 8;

    __shared__ float hp_d[4][32][49];
    __shared__ float xq_d[4][32][49];

    // ---- hp = h_t · w_hh^T ----
    f32x4 hp[6];
#pragma unroll
    for (int i = 0; i < 6; ++i) hp[i] = (f32x4){0.f, 0.f, 0.f, 0.f};
    {
        const unsigned short* Ah = hB + (size_t)(t & 1) * (NB * NH)
                                      + (size_t)(bb * 32 + col) * NH + koff;
        const unsigned short* W0 = w_hh + (size_t)(0 * NH + hc * 16 + col) * NH + koff;
        const unsigned short* W1 = w_hh + (size_t)(1 * NH + hc * 16 + col) * NH + koff;
        const unsigned short* W2 = w_hh + (size_t)(2 * NH + hc * 16 + col) * NH + koff;
#pragma unroll
        for (int s = 0; s < 8; ++s) {
            short8 a0 = *(const short8*)(Ah + s * 32);
            short8 a1 = *(const short8*)(Ah + 16 * NH + s * 32);
            short8 b0 = *(const short8*)(W0 + s * 32);
            short8 b1 = *(const short8*)(W1 + s * 32);
            short8 b2 = *(const short8*)(W2 + s * 32);
            hp[0] = __builtin_amdgcn_mfma_f32_16x16x32_bf16(a0, b0, hp[0], 0, 0, 0);
            hp[1] = __builtin_amdgcn_mfma_f32_16x16x32_bf16(a0, b1, hp[1], 0, 0, 0);
            hp[2] = __builtin_amdgcn_mfma_f32_16x16x32_bf16(a0, b2, hp[2], 0, 0, 0);
            hp[3] = __builtin_amdgcn_mfma_f32_16x16x32_bf16(a1, b0, hp[3], 0, 0, 0);
            hp[4] = __builtin_amdgcn_mfma_f32_16x16x32_bf16(a1, b1, hp[4], 0, 0, 0);
            hp[5] = __builtin_amdgcn_mfma_f32_16x16x32_bf16(a1, b2, hp[5], 0, 0, 0);
        }
    }

    // ---- xq = x_{t+1} · w_ih^T (for next step) ----
    f32x4 xq[6];
#pragma unroll
    for (int i = 0; i < 6; ++i) xq[i] = (f32x4){0.f, 0.f, 0.f, 0.f};
    if (t + 1 < NT)
        xq_gemm(xbf + (size_t)(t + 1) * NH, w_ih, bb, hc, col, koff, xq);

    // ---- dump k-split partials ----
#pragma unroll
    for (int m = 0; m < 2; ++m)
#pragma unroll
        for (int n = 0; n < 3; ++n)
#pragma unroll
            for (int i = 0; i < 4; ++i) {
                hp_d[kw][m * 16 + q * 4 + i][n * 16 + col] = hp[m * 3 + n][i];
                xq_d[kw][m * 16 + q * 4 + i][n * 16 + col] = xq[m * 3 + n][i];
            }
    __syncthreads();

    // ---- gates epilogue: 512 outputs, 2 per thread ----
    const int b = tid >> 3, h2 = (tid & 7) * 2, bg = bb * 32 + b;
#pragma unroll
    for (int e = 0; e < 2; ++e) {
        const int hl = h2 + e;
        const int hg = hc * 16 + hl;

        const float* xps = xp + (size_t)(t & 1) * (NB * NG) + (size_t)bg * NG;
        float xr = xps[hg]          + b_ih[hg];
        float xz = xps[NH + hg]     + b_ih[NH + hg];
        float xn = xps[2 * NH + hg] + b_ih[2 * NH + hg];
        float hr = b_hh[hg];
        float hz = b_hh[NH + hg];
        float hn = b_hh[2 * NH + hg];
#pragma unroll
        for (int c = 0; c < 4; ++c) {
            hr += hp_d[c][b][hl];
            hz += hp_d[c][b][16 + hl];
            hn += hp_d[c][b][32 + hl];
        }
        const float r = sigm_f(xr + hr);
        const float z = sigm_f(xz + hz);
        const float n = tanh_f(xn + r * hn);
        const float hprev = hF[(size_t)(t & 1) * (NB * NH) + (size_t)bg * NH + hg];
        const float hnew  = (1.f - z) * n + z * hprev;

        hF[(size_t)((t + 1) & 1) * (NB * NH) + (size_t)bg * NH + hg] = hnew;
        hB[(size_t)((t + 1) & 1) * (NB * NH) + (size_t)bg * NH + hg] = f2bf(hnew);
        out[((size_t)bg * NT + t) * NH + hg] = hnew;

        if (t + 1 < NT) {
            float s0 = 0.f, s1 = 0.f, s2 = 0.f;
#pragma unroll
            for (int c = 0; c < 4; ++c) {
                s0 += xq_d[c][b][hl];
                s1 += xq_d[c][b][16 + hl];
                s2 += xq_d[c][b][32 + hl];
            }
            float* xpd = xp + (size_t)((t + 1) & 1) * (NB * NG) + (size_t)bg * NG;
            xpd[hg]          = s0;
            xpd[NH + hg]     = s1;
            xpd[2 * NH + hg] = s2;
        }
    }
}

// ===========================================================================
// FALLBACK PATH (fp32 VALU, R5-validated) — 1 MB ws
// ===========================================================================

__global__ __launch_bounds__(256) void xproj_f32_kernel(
    const float* __restrict__ actions, const float* __restrict__ fc_w,
    const float* __restrict__ fc_b, float* __restrict__ xbuf)
{
    const int bt = blockIdx.x, tid = threadIdx.x;
    const float* ap = actions + (size_t)bt * NA;
    float a[8];
#pragma unroll
    for (int i = 0; i < 8; ++i) a[i] = ap[i];
    const int h0 = tid * 4;
    float4 r;
    float* rp = &r.x;
#pragma unroll
    for (int j = 0; j < 4; ++j) {
        const float* wp = fc_w + (size_t)(h0 + j) * NA;
        float acc = fc_b[h0 + j];
#pragma unroll
        for (int i = 0; i < 8; ++i) acc += a[i] * wp[i];
        rp[j] = fmaxf(acc, 0.f);
    }
    *(float4*)(xbuf + (size_t)bt * NH + h0) = r;
}

__global__ __launch_bounds__(512) void hinit_kernel(
    const float* __restrict__ hidden0, float* __restrict__ hF)
{
    const int i = blockIdx.x * 512 + threadIdx.x;
    hF[i] = hidden0[i];
}

__global__ __launch_bounds__(512) void gru_step_valu(
    float* xout, const float* __restrict__ w_ih, const float* __restrict__ w_hh,
    const float* __restrict__ b_ih, const float* __restrict__ b_hh,
    float* __restrict__ hF, int t)
{
    const int tid = threadIdx.x;
    const int b = tid >> 4, hl = tid & 15;
    const int bb = blockIdx.x >> 6, hc = blockIdx.x & 63;
    const int bg = bb * 32 + b, hg = hc * 16 + hl;

    const float* hrow = hF + (size_t)(t & 1) * (NB * NH) + (size_t)bg * NH;
    const float* xrow = xout + ((size_t)bg * NT + t) * NH;
    const float* wrh = w_hh + (size_t)(0 * NH + hg) * NH;
    const float* wzh = w_hh + (size_t)(1 * NH + hg) * NH;
    const float* wnh = w_hh + (size_t)(2 * NH + hg) * NH;
    const float* wrx = w_ih + (size_t)(0 * NH + hg) * NH;
    const float* wzx = w_ih + (size_t)(1 * NH + hg) * NH;
    const float* wnx = w_ih + (size_t)(2 * NH + hg) * NH;

    float hr = 0.f, hz = 0.f, hn = 0.f, xr = 0.f, xz = 0.f, xn = 0.f;
#pragma unroll 4
    for (int k = 0; k < NH; k += 4) {
        float4 hv = *(const float4*)(hrow + k);
        float4 xv = *(const float4*)(xrow + k);
        float4 w;
        w = *(const float4*)(wrh + k); hr += hv.x*w.x + hv.y*w.y + hv.z*w.z + hv.w*w.w;
        w = *(const float4*)(wzh + k); hz += hv.x*w.x + hv.y*w.y + hv.z*w.z + hv.w*w.w;
        w = *(const float4*)(wnh + k); hn += hv.x*w.x + hv.y*w.y + hv.z*w.z + hv.w*w.w;
        w = *(const float4*)(wrx + k); xr += xv.x*w.x + xv.y*w.y + xv.z*w.z + xv.w*w.w;
        w = *(const float4*)(wzx + k); xz += xv.x*w.x + xv.y*w.y + xv.z*w.z + xv.w*w.w;
        w = *(const float4*)(wnx + k); xn += xv.x*w.x + xv.y*w.y + xv.z*w.z + xv.w*w.w;
    }
    const float r = sigm_f(xr + b_ih[hg] + hr + b_hh[hg]);
    const float z = sigm_f(xz + b_ih[NH + hg] + hz + b_hh[NH + hg]);
    const float n = tanh_f(xn + b_ih[2 * NH + hg] + r * (hn + b_hh[2 * NH + hg]));
    const float hprev = hrow[hg];
    const float hnew  = (1.f - z) * n + z * hprev;
    hF[(size_t)((t + 1) & 1) * (NB * NH) + (size_t)bg * NH + hg] = hnew;
    if (t > 0)
        xout[((size_t)bg * NT + (t - 1)) * NH + hg] = hprev;
}

__global__ __launch_bounds__(512) void tail_kernel(
    const float* __restrict__ hF, float* __restrict__ xout)
{
    const int i = blockIdx.x * 512 + threadIdx.x;
    const int b = i >> 10, h = i & (NH - 1);
    xout[((size_t)b * NT + (NT - 1)) * NH + h] = hF[i];
}

// ===========================================================================

extern "C" void kernel_launch(void* const* d_in, const int* in_sizes, int n_in,
                              void* d_out, int out_size, void* d_ws, size_t ws_size,
                              hipStream_t stream)
{
    (void)in_sizes; (void)n_in; (void)out_size;

    const float* actions = (const float*)d_in[0];
    const float* hidden  = (const float*)d_in[1];
    const float* fc_w    = (const float*)d_in[2];
    const float* fc_b    = (const float*)d_in[3];
    const float* w_ih    = (const float*)d_in[4];
    const float* w_hh    = (const float*)d_in[5];
    const float* b_ih    = (const float*)d_in[6];
    const float* b_hh    = (const float*)d_in[7];

    float* outp = (float*)d_out;

    // fast-path ws layout:
    //   wih_bf 6,291,456 | whh_bf 6,291,456 | xbf 67,108,864
    //   | xp 3,145,728 | hF 1,048,576 | hB 524,288   = 84,410,368 B
    const size_t NEED = 84410368;

    if (ws_size >= NEED) {
        unsigned short* wih_bf = (unsigned short*)d_ws;
        unsigned short* whh_bf = (unsigned short*)((char*)d_ws + 6291456);
        unsigned short* xbf    = (unsigned short*)((char*)d_ws + 12582912);
        float*          xp     = (float*)((char*)d_ws + 79691776);
        float*          hF     = (float*)((char*)d_ws + 82837504);
        unsigned short* hB     = (unsigned short*)((char*)d_ws + 83886080);

        wconv_kernel<<<dim3(3072), dim3(256), 0, stream>>>(w_ih, wih_bf, NG * NH);
        wconv_kernel<<<dim3(3072), dim3(256), 0, stream>>>(w_hh, whh_bf, NG * NH);
        xproj_bf16_kernel<<<dim3(NB * NT), dim3(256), 0, stream>>>(actions, fc_w, fc_b, xbf);
        gru_init_kernel<<<dim3(256), dim3(256), 0, stream>>>(xbf, hidden, wih_bf, xp, hF, hB);
        for (int t = 0; t < NT; ++t)
            gru_step_kernel<<<dim3(256), dim3(256), 0, stream>>>(outp, xbf, wih_bf, whh_bf,
                                                                 b_ih, b_hh, xp, hF, hB, t);
    } else {
        float* hF = (float*)d_ws;   // 1 MB
        xproj_f32_kernel<<<dim3(NB * NT), dim3(256), 0, stream>>>(actions, fc_w, fc_b, outp);
        hinit_kernel<<<dim3(256), dim3(512), 0, stream>>>(hidden, hF);
        for (int t = 0; t < NT; ++t)
            gru_step_valu<<<dim3(256), dim3(512), 0, stream>>>(outp, w_ih, w_hh,
                                                               b_ih, b_hh, hF, t);
        tail_kernel<<<dim3(256), dim3(512), 0, stream>>>(hF, outp);
    }
}